// Round 5
// baseline (891.925 us; speedup 1.0000x reference)
//
#include <hip/hip_runtime.h>
#include <stdint.h>

#define NB 32
#define NS 40
#define NT 60
#define NH 256
#define NF 64
#define NDIN 320
#define NG 1024
#define NSB 1280
#define NOUT 128

typedef __bf16 bf16x8 __attribute__((ext_vector_type(8)));
typedef float f32x4 __attribute__((ext_vector_type(4)));

union bfrag { bf16x8 v; uint16_t u[8]; uint4 q; uint64_t d[2]; };
union f4arr { float4 v; float a[4]; };

__device__ __forceinline__ uint16_t f2bf(float f) {
  uint32_t u = __float_as_uint(f);
  u += 0x7fffu + ((u >> 16) & 1u);
  return (uint16_t)(u >> 16);
}
__device__ __forceinline__ float bf2f(uint16_t h) {
  return __uint_as_float(((uint32_t)h) << 16);
}
__device__ __forceinline__ float sigf(float x) { return 1.0f / (1.0f + expf(-x)); }

__device__ __forceinline__ uint64_t ld_agent_u64(const uint64_t* p) {
  return __hip_atomic_load(p, __ATOMIC_RELAXED, __HIP_MEMORY_SCOPE_AGENT);
}
__device__ __forceinline__ void st_agent_u64(uint64_t* p, uint64_t v) {
  __hip_atomic_store(p, v, __ATOMIC_RELAXED, __HIP_MEMORY_SCOPE_AGENT);
}

// ---------------- mask dtype detector: 0=int32, 1=bytes(bool), 2=float32 ----
__global__ void k_detect(const uint32_t* __restrict__ xm, int* __restrict__ flag) {
  __shared__ int s_notint, s_notflt;
  if (threadIdx.x == 0) { s_notint = 0; s_notflt = 0; }
  __syncthreads();
  int notint = 0, notflt = 0;
  for (int i = threadIdx.x; i < 19200; i += 256) {   // 76800 bytes: safe all dtypes
    uint32_t v = xm[i];
    if (v > 1u) notint = 1;
    if (v != 0u && v != 0x3f800000u) notflt = 1;
  }
  if (notint) atomicOr(&s_notint, 1);
  if (notflt) atomicOr(&s_notflt, 1);
  __syncthreads();
  if (threadIdx.x == 0) {
    int f;
    if (!s_notint) f = 0;
    else if (!s_notflt) f = 2;
    else f = 1;
    *flag = f;
  }
}

// -------- wih -> hi/lo bf16 planes: layout [hi: dir0,dir1][lo: dir0,dir1] ----
__global__ void k_prep(const float* __restrict__ wf, const float* __restrict__ wb,
                       uint16_t* __restrict__ outw) {
  const int n = NG * NDIN;
  for (int idx = blockIdx.x * 256 + threadIdx.x; idx < 2 * n; idx += gridDim.x * 256) {
    float v = (idx < n) ? wf[idx] : wb[idx - n];
    uint16_t hi = f2bf(v);
    outw[idx] = hi;
    outw[2 * n + idx] = f2bf(v - bf2f(hi));
  }
}

// ---------------- attention pooling: one block per (b,s) --------------------
__global__ __launch_bounds__(256) void k_attn(
    const int* __restrict__ x, const void* __restrict__ xmask,
    const float* __restrict__ xfeat, const int* __restrict__ slen,
    const float* __restrict__ emb, const float* __restrict__ attn_w,
    uint16_t* __restrict__ Xb, const int* __restrict__ flagp)
{
  int bs = blockIdx.x;
  int b = bs / NS, s = bs % NS;
  int tid = threadIdx.x;
  uint16_t* Xh = Xb + (size_t)(s * NB + b) * NDIN;
  uint16_t* Xl = Xh + (size_t)NSB * NDIN;
  int len = slen[b];
  if (s >= len) {
    for (int i = tid; i < NDIN; i += 256) { Xh[i] = 0; Xl[i] = 0; }
    return;
  }
  __shared__ __attribute__((aligned(16))) float sw[NH];
  __shared__ float salpha[NT];
  __shared__ int sidx[NT];
  __shared__ unsigned char svalid[NT];
  __shared__ __attribute__((aligned(16))) uint16_t es[NT][NH];
  sw[tid] = attn_w[tid];
  int flag = *flagp;
  if (tid < NT) {
    int mi = bs * NT + tid;
    sidx[tid] = x[mi];
    int mv;
    if (flag == 1)      mv = ((const unsigned char*)xmask)[mi];
    else if (flag == 2) mv = (((const float*)xmask)[mi] != 0.0f) ? 1 : 0;
    else                mv = ((const int*)xmask)[mi];
    svalid[tid] = (mv == 0) ? 1 : 0;
  }
  __syncthreads();
  int wave = tid >> 6, lane = tid & 63;
  for (int t = wave; t < NT; t += 4) {
    float d = 0.0f;
    if (svalid[t]) {
      const float* er = emb + (size_t)sidx[t] * NH;
      float4 e4 = ((const float4*)er)[lane];
      float4 w4 = ((const float4*)sw)[lane];
      uint16_t* ed = &es[t][lane * 4];
      ed[0] = f2bf(e4.x); ed[1] = f2bf(e4.y); ed[2] = f2bf(e4.z); ed[3] = f2bf(e4.w);
      d = e4.x * w4.x + e4.y * w4.y + e4.z * w4.z + e4.w * w4.w;
      #pragma unroll
      for (int o = 32; o > 0; o >>= 1) d += __shfl_down(d, o);
    }
    if (lane == 0) salpha[t] = d;
  }
  __syncthreads();
  if (tid < 64) {                       // wave-parallel softmax over <=60 tokens
    int valid = (tid < NT) && svalid[tid];
    float v = valid ? salpha[tid] : -1e30f;
    float m = v;
    #pragma unroll
    for (int o = 32; o > 0; o >>= 1) m = fmaxf(m, __shfl_xor(m, o));
    float e = valid ? expf(v - m) : 0.0f;
    float ssum = e;
    #pragma unroll
    for (int o = 32; o > 0; o >>= 1) ssum += __shfl_xor(ssum, o);
    if (tid < NT) salpha[tid] = e / ssum;
  }
  __syncthreads();
  float acc = 0.0f;                     // emb_part, tid == h-index
  for (int t = 0; t < NT; t++) {
    float a = salpha[t];
    if (a != 0.0f) acc += a * bf2f(es[t][tid]);
  }
  {
    uint16_t hi = f2bf(acc);
    Xh[tid] = hi; Xl[tid] = f2bf(acc - bf2f(hi));
  }
  if (tid < NF) {
    float fa = 0.0f;
    const float* fp = xfeat + (size_t)bs * NT * NF + tid;
    for (int t = 0; t < NT; t++) if (svalid[t]) fa += fp[t * NF];
    uint16_t hi = f2bf(fa);
    Xh[NH + tid] = hi; Xl[NH + tid] = f2bf(fa - bf2f(hi));
  }
}

// ------- gbase = X @ wih^T + bih + bhh, hi/lo split operands ----------------
__global__ __launch_bounds__(512) void k_gbase(
    const uint16_t* __restrict__ Xb, const uint16_t* __restrict__ wihb,
    const float* __restrict__ bih_f, const float* __restrict__ bhh_f,
    const float* __restrict__ bih_b, const float* __restrict__ bhh_b,
    float* __restrict__ gbase)
{
  const int n = NG * NDIN;
  int wave = threadIdx.x >> 6, lane = threadIdx.x & 63;
  int job = blockIdx.x * 8 + wave;
  int dir = job / 1280;
  int r = job % 1280;
  int nt = r % 64, ms = r / 64;
  int m0 = ms * 64;
  const uint16_t* Wh = wihb + (size_t)dir * n;
  const uint16_t* Wl = Wh + (size_t)2 * n;
  const uint16_t* Ah = Xb;
  const uint16_t* Al = Xb + (size_t)NSB * NDIN;
  int lrow = lane & 15, lk = (lane >> 4) * 8;
  f32x4 acc0 = {0,0,0,0}, acc1 = acc0, acc2 = acc0, acc3 = acc0;
  for (int kk = 0; kk < 10; kk++) {
    int k0 = kk * 32 + lk;
    bfrag bh, bl, ah0, ah1, ah2, ah3, al0, al1, al2, al3;
    bh.q = *(const uint4*)(Wh + (size_t)(nt * 16 + lrow) * NDIN + k0);
    bl.q = *(const uint4*)(Wl + (size_t)(nt * 16 + lrow) * NDIN + k0);
    ah0.q = *(const uint4*)(Ah + (size_t)(m0 +  0 + lrow) * NDIN + k0);
    ah1.q = *(const uint4*)(Ah + (size_t)(m0 + 16 + lrow) * NDIN + k0);
    ah2.q = *(const uint4*)(Ah + (size_t)(m0 + 32 + lrow) * NDIN + k0);
    ah3.q = *(const uint4*)(Ah + (size_t)(m0 + 48 + lrow) * NDIN + k0);
    al0.q = *(const uint4*)(Al + (size_t)(m0 +  0 + lrow) * NDIN + k0);
    al1.q = *(const uint4*)(Al + (size_t)(m0 + 16 + lrow) * NDIN + k0);
    al2.q = *(const uint4*)(Al + (size_t)(m0 + 32 + lrow) * NDIN + k0);
    al3.q = *(const uint4*)(Al + (size_t)(m0 + 48 + lrow) * NDIN + k0);
    acc0 = __builtin_amdgcn_mfma_f32_16x16x32_bf16(ah0.v, bh.v, acc0, 0, 0, 0);
    acc0 = __builtin_amdgcn_mfma_f32_16x16x32_bf16(ah0.v, bl.v, acc0, 0, 0, 0);
    acc0 = __builtin_amdgcn_mfma_f32_16x16x32_bf16(al0.v, bh.v, acc0, 0, 0, 0);
    acc1 = __builtin_amdgcn_mfma_f32_16x16x32_bf16(ah1.v, bh.v, acc1, 0, 0, 0);
    acc1 = __builtin_amdgcn_mfma_f32_16x16x32_bf16(ah1.v, bl.v, acc1, 0, 0, 0);
    acc1 = __builtin_amdgcn_mfma_f32_16x16x32_bf16(al1.v, bh.v, acc1, 0, 0, 0);
    acc2 = __builtin_amdgcn_mfma_f32_16x16x32_bf16(ah2.v, bh.v, acc2, 0, 0, 0);
    acc2 = __builtin_amdgcn_mfma_f32_16x16x32_bf16(ah2.v, bl.v, acc2, 0, 0, 0);
    acc2 = __builtin_amdgcn_mfma_f32_16x16x32_bf16(al2.v, bh.v, acc2, 0, 0, 0);
    acc3 = __builtin_amdgcn_mfma_f32_16x16x32_bf16(ah3.v, bh.v, acc3, 0, 0, 0);
    acc3 = __builtin_amdgcn_mfma_f32_16x16x32_bf16(ah3.v, bl.v, acc3, 0, 0, 0);
    acc3 = __builtin_amdgcn_mfma_f32_16x16x32_bf16(al3.v, bh.v, acc3, 0, 0, 0);
  }
  int col = nt * 16 + lrow;
  float bias = dir ? (bih_b[col] + bhh_b[col]) : (bih_f[col] + bhh_f[col]);
  float* gb = gbase + (size_t)dir * NSB * NG;
  int rb = (lane >> 4) * 4;
  #pragma unroll
  for (int rr = 0; rr < 4; rr++) {
    gb[(size_t)(m0 +  0 + rb + rr) * NG + col] = acc0[rr] + bias;
    gb[(size_t)(m0 + 16 + rb + rr) * NG + col] = acc1[rr] + bias;
    gb[(size_t)(m0 + 32 + rb + rr) * NG + col] = acc2[rr] + bias;
    gb[(size_t)(m0 + 48 + rb + rr) * NG + col] = acc3[rr] + bias;
  }
}

// ---------------- persistent bidirectional LSTM: 8 blocks -------------------
// hbuf layout: [dir][parity][plane hi/lo][NB][NH]; all h/flag traffic via
// agent-scope relaxed atomics (L3-coherent, no fences). No LDS h-staging:
// MFMA A-fragments are loaded directly from L3. Per-part step flags; polls
// skip own part. __launch_bounds__(512,2) keeps 128 weight VGPRs resident.
__global__ __launch_bounds__(512, 2) void k_lstm(
    const float* __restrict__ whh_f_, const float* __restrict__ whh_b_,
    const float* __restrict__ gbase, const int* __restrict__ slen,
    uint16_t* __restrict__ hbuf, int* __restrict__ bars)
{
  int wg = blockIdx.x;
  int dir = wg >> 2, p = wg & 3;
  int u0 = p * 64;
  int tid = threadIdx.x, wave = tid >> 6, lane = tid & 63;
  const float* Wr = dir ? whh_b_ : whh_f_;
  const float* gb = gbase + (size_t)dir * NSB * NG;
  uint16_t* hb = hbuf + (size_t)dir * 4 * NB * NH;   // [parity][plane][NB][NH]
  int* sf = bars + dir * 8;

  __shared__ float gbuf[NB][260];
  __shared__ float cbuf[NB][64];
  __shared__ int slen_s[NB];

  if (tid < NB) slen_s[tid] = slen[tid];
  for (int i2 = tid; i2 < NB * 64; i2 += 512) ((float*)cbuf)[i2 & (NB * 64 - 1)] = 0.0f;

  int lrow = lane & 15, lkb = (lane >> 4) * 8;
  // whh fragments, hi+lo: wave owns n-tiles {2w, 2w+1}; local n = gate*64 + unit
  bfrag wh0[8], wh1[8], wl0[8], wl1[8];
  {
    int nl0 = wave * 32 + lrow;
    int nl1 = nl0 + 16;
    const float* wrow0 = Wr + (size_t)((nl0 >> 6) * 256 + u0 + (nl0 & 63)) * NH;
    const float* wrow1 = Wr + (size_t)((nl1 >> 6) * 256 + u0 + (nl1 & 63)) * NH;
    #pragma unroll
    for (int kk = 0; kk < 8; kk++) {
      int k0 = kk * 32 + lkb;
      bfrag t0h, t0l, t1h, t1l;
      #pragma unroll
      for (int e = 0; e < 8; e++) {
        float v0 = wrow0[k0 + e], v1 = wrow1[k0 + e];
        uint16_t h0_ = f2bf(v0), h1_ = f2bf(v1);
        t0h.u[e] = h0_; t0l.u[e] = f2bf(v0 - bf2f(h0_));
        t1h.u[e] = h1_; t1l.u[e] = f2bf(v1 - bf2f(h1_));
      }
      wh0[kk] = t0h; wl0[kk] = t0l; wh1[kk] = t1h; wl1[kk] = t1l;
    }
  }
  // zero h parity-0, both planes, this part's 64-unit slice
  for (int i2 = tid; i2 < NB * 32; i2 += 512) {
    int pl = i2 >> 9, r = i2 & 511;
    int b2 = r >> 4, c3 = r & 15;             // 16 u64 per 64-unit slice
    st_agent_u64((uint64_t*)(hb + ((size_t)pl * NB + b2) * NH + u0) + c3, 0ull);
  }
  asm volatile("s_waitcnt vmcnt(0)" ::: "memory");
  __syncthreads();
  if (tid == 0) __hip_atomic_store(&sf[p], 1, __ATOMIC_RELAXED, __HIP_MEMORY_SCOPE_AGENT);

  int b_ = tid >> 4;
  int j0 = (tid & 15) * 4;

  for (int i = 0; i < NS; i++) {
    int t = dir ? (NS - 1 - i) : i;
    const uint16_t* hp = hb + (size_t)(i & 1) * 2 * NB * NH;
    // ---- prefetch this step's gbase row (plain) + own-slice passthrough h --
    const float* grow = gb + ((size_t)t * NB + b_) * NG + u0;
    f4arr g0, g1, g2, g3;
    g0.v = *(const float4*)(grow + j0);
    g1.v = *(const float4*)(grow + 256 + j0);
    g2.v = *(const float4*)(grow + 512 + j0);
    g3.v = *(const float4*)(grow + 768 + j0);
    uint64_t ph  = ld_agent_u64((const uint64_t*)(hp + (size_t)b_ * NH + u0 + j0));
    uint64_t plo = ld_agent_u64((const uint64_t*)(hp + (size_t)(NB + b_) * NH + u0 + j0));
    // ---- per-wave poll: other 3 parts published h for this step ----
    {
      int need = i + 1;
      long spins = 0;
      for (;;) {
        int ok = 1;
        #pragma unroll
        for (int q = 0; q < 4; q++) {
          if (q == p) continue;
          int v = __hip_atomic_load(&sf[q], __ATOMIC_RELAXED, __HIP_MEMORY_SCOPE_AGENT);
          ok &= (v >= need);
        }
        if (ok) break;
        if (++spins > (1L << 22)) break;
        __builtin_amdgcn_s_sleep(1);
      }
    }
    // ---- A-fragments straight from L3 + recurrent MFMA ----
    f32x4 acc00 = {0,0,0,0}, acc01 = acc00, acc10 = acc00, acc11 = acc00;
    #pragma unroll
    for (int kk = 0; kk < 8; kk++) {
      int k0 = kk * 32 + lkb;
      const uint64_t* r0h = (const uint64_t*)(hp + (size_t)lrow * NH + k0);
      const uint64_t* r1h = (const uint64_t*)(hp + (size_t)(16 + lrow) * NH + k0);
      const uint64_t* r0l = (const uint64_t*)(hp + (size_t)(NB + lrow) * NH + k0);
      const uint64_t* r1l = (const uint64_t*)(hp + (size_t)(NB + 16 + lrow) * NH + k0);
      bfrag ah0, ah1, al0, al1;
      ah0.d[0] = ld_agent_u64(r0h);     ah0.d[1] = ld_agent_u64(r0h + 1);
      ah1.d[0] = ld_agent_u64(r1h);     ah1.d[1] = ld_agent_u64(r1h + 1);
      al0.d[0] = ld_agent_u64(r0l);     al0.d[1] = ld_agent_u64(r0l + 1);
      al1.d[0] = ld_agent_u64(r1l);     al1.d[1] = ld_agent_u64(r1l + 1);
      acc00 = __builtin_amdgcn_mfma_f32_16x16x32_bf16(ah0.v, wh0[kk].v, acc00, 0, 0, 0);
      acc00 = __builtin_amdgcn_mfma_f32_16x16x32_bf16(ah0.v, wl0[kk].v, acc00, 0, 0, 0);
      acc00 = __builtin_amdgcn_mfma_f32_16x16x32_bf16(al0.v, wh0[kk].v, acc00, 0, 0, 0);
      acc01 = __builtin_amdgcn_mfma_f32_16x16x32_bf16(ah0.v, wh1[kk].v, acc01, 0, 0, 0);
      acc01 = __builtin_amdgcn_mfma_f32_16x16x32_bf16(ah0.v, wl1[kk].v, acc01, 0, 0, 0);
      acc01 = __builtin_amdgcn_mfma_f32_16x16x32_bf16(al0.v, wh1[kk].v, acc01, 0, 0, 0);
      acc10 = __builtin_amdgcn_mfma_f32_16x16x32_bf16(ah1.v, wh0[kk].v, acc10, 0, 0, 0);
      acc10 = __builtin_amdgcn_mfma_f32_16x16x32_bf16(ah1.v, wl0[kk].v, acc10, 0, 0, 0);
      acc10 = __builtin_amdgcn_mfma_f32_16x16x32_bf16(al1.v, wh0[kk].v, acc10, 0, 0, 0);
      acc11 = __builtin_amdgcn_mfma_f32_16x16x32_bf16(ah1.v, wh1[kk].v, acc11, 0, 0, 0);
      acc11 = __builtin_amdgcn_mfma_f32_16x16x32_bf16(ah1.v, wl1[kk].v, acc11, 0, 0, 0);
      acc11 = __builtin_amdgcn_mfma_f32_16x16x32_bf16(al1.v, wh1[kk].v, acc11, 0, 0, 0);
    }
    {
      int nl0 = wave * 32 + lrow, nl1 = nl0 + 16;
      int rb = (lane >> 4) * 4;
      #pragma unroll
      for (int rr = 0; rr < 4; rr++) {
        gbuf[rb + rr][nl0]      = acc00[rr];
        gbuf[rb + rr][nl1]      = acc01[rr];
        gbuf[16 + rb + rr][nl0] = acc10[rr];
        gbuf[16 + rb + rr][nl1] = acc11[rr];
      }
    }
    __syncthreads();
    // ---- pointwise: thread owns (b, 4 units); g + passthrough in registers --
    {
      int upd = (t < slen_s[b_]) ? 1 : 0;
      uint32_t hi0 = 0, hi1 = 0, lo0 = 0, lo1 = 0;
      #pragma unroll
      for (int e = 0; e < 4; e++) {
        int j = j0 + e;
        float gi = gbuf[b_][j]       + g0.a[e];
        float gf = gbuf[b_][64 + j]  + g1.a[e];
        float gg = gbuf[b_][128 + j] + g2.a[e];
        float go = gbuf[b_][192 + j] + g3.a[e];
        float c_old = cbuf[b_][j];
        float c2v = sigf(gf) * c_old + sigf(gi) * tanhf(gg);
        float h2v = sigf(go) * tanhf(c2v);
        cbuf[b_][j] = upd ? c2v : c_old;
        uint16_t hb_, lb_;
        if (upd) { hb_ = f2bf(h2v); lb_ = f2bf(h2v - bf2f(hb_)); }
        else     { hb_ = (uint16_t)(ph >> (16 * e)); lb_ = (uint16_t)(plo >> (16 * e)); }
        if (e < 2) { hi0 |= ((uint32_t)hb_) << (16 * e);       lo0 |= ((uint32_t)lb_) << (16 * e); }
        else       { hi1 |= ((uint32_t)hb_) << (16 * (e - 2)); lo1 |= ((uint32_t)lb_) << (16 * (e - 2)); }
      }
      size_t pbase = (size_t)(((i + 1) & 1) * 2) * NB * NH;
      st_agent_u64((uint64_t*)(hb + pbase + (size_t)b_ * NH + u0 + j0),
                   ((uint64_t)hi1 << 32) | hi0);
      st_agent_u64((uint64_t*)(hb + pbase + (size_t)(NB + b_) * NH + u0 + j0),
                   ((uint64_t)lo1 << 32) | lo0);
    }
    asm volatile("s_waitcnt vmcnt(0)" ::: "memory");   // drain h stores (per wave)
    __syncthreads();                                    // all waves drained
    if (tid == 0)
      __hip_atomic_store(&sf[p], i + 2, __ATOMIC_RELAXED, __HIP_MEMORY_SCOPE_AGENT);
  }
}

// ---------------- FC + BatchNorm + ReLU + log_softmax(axis=0) ---------------
__global__ __launch_bounds__(1024) void k_final(
    const uint16_t* __restrict__ hbuf, const float* __restrict__ fc_w,
    const float* __restrict__ fc_b, const float* __restrict__ gamma_,
    const float* __restrict__ beta_, float* __restrict__ outp)
{
  __shared__ float hid[NB][512];
  __shared__ float ylds[NB][NOUT];
  int tid = threadIdx.x;
  const uint16_t* hf  = hbuf;                       // dir0 parity0 (hi +0, lo +NB*NH)
  const uint16_t* hbk = hbuf + (size_t)4 * NB * NH; // dir1 parity0
  for (int idx = tid; idx < NB * 512; idx += 1024) {
    int bb = idx >> 9, k = idx & 511;
    int bsrc = 2 * (bb & 15) + (k >> 8);
    int hcol = k & 255;
    const uint16_t* src = (bb < 16) ? hf : hbk;
    hid[bb][k] = bf2f(src[bsrc * NH + hcol]) + bf2f(src[NB * NH + bsrc * NH + hcol]);
  }
  __syncthreads();
  int o = tid & 127, b0 = tid >> 7;
  float a0 = 0, a1 = 0, a2 = 0, a3 = 0;
  const float4* wrow = (const float4*)(fc_w + (size_t)o * 512);
  for (int k4 = 0; k4 < 128; k4++) {
    float4 w = wrow[k4];
    float4 h0 = *(const float4*)(&hid[b0][k4 * 4]);
    float4 h1 = *(const float4*)(&hid[b0 + 8][k4 * 4]);
    float4 h2 = *(const float4*)(&hid[b0 + 16][k4 * 4]);
    float4 h3 = *(const float4*)(&hid[b0 + 24][k4 * 4]);
    a0 += w.x * h0.x + w.y * h0.y + w.z * h0.z + w.w * h0.w;
    a1 += w.x * h1.x + w.y * h1.y + w.z * h1.z + w.w * h1.w;
    a2 += w.x * h2.x + w.y * h2.y + w.z * h2.z + w.w * h2.w;
    a3 += w.x * h3.x + w.y * h3.y + w.z * h3.z + w.w * h3.w;
  }
  float bias = fc_b[o];
  ylds[b0][o]      = a0 + bias;
  ylds[b0 + 8][o]  = a1 + bias;
  ylds[b0 + 16][o] = a2 + bias;
  ylds[b0 + 24][o] = a3 + bias;
  __syncthreads();
  if (tid < NOUT) {
    float mu = 0;
    for (int bb = 0; bb < NB; bb++) mu += ylds[bb][tid];
    mu *= (1.0f / NB);
    float var = 0;
    for (int bb = 0; bb < NB; bb++) { float d = ylds[bb][tid] - mu; var += d * d; }
    var *= (1.0f / NB);
    float g = gamma_[tid], be = beta_[tid];
    float inv = 1.0f / sqrtf(var + 1e-5f);
    float ym = -1e30f;
    for (int bb = 0; bb < NB; bb++) {
      float y = g * (ylds[bb][tid] - mu) * inv + be;
      y = fmaxf(y, 0.0f);
      ylds[bb][tid] = y;
      if (y > ym) ym = y;
    }
    float se = 0;
    for (int bb = 0; bb < NB; bb++) se += expf(ylds[bb][tid] - ym);
    float lse = ym + logf(se);
    for (int bb = 0; bb < NB; bb++) outp[bb * NOUT + tid] = ylds[bb][tid] - lse;
  }
}

extern "C" void kernel_launch(void* const* d_in, const int* in_sizes, int n_in,
                              void* d_out, int out_size, void* d_ws, size_t ws_size,
                              hipStream_t stream) {
  (void)in_sizes; (void)n_in; (void)out_size; (void)ws_size;
  const int*   x      = (const int*)  d_in[0];
  const void*  xmask  =               d_in[1];
  const float* xfeat  = (const float*)d_in[2];
  const int*   slen   = (const int*)  d_in[3];
  const float* emb    = (const float*)d_in[6];
  const float* attn_w = (const float*)d_in[7];
  const float* wih_f  = (const float*)d_in[9];
  const float* whh_f  = (const float*)d_in[10];
  const float* bih_f  = (const float*)d_in[11];
  const float* bhh_f  = (const float*)d_in[12];
  const float* wih_b  = (const float*)d_in[13];
  const float* whh_b  = (const float*)d_in[14];
  const float* bih_b  = (const float*)d_in[15];
  const float* bhh_b  = (const float*)d_in[16];
  const float* fc_w   = (const float*)d_in[17];
  const float* fc_b   = (const float*)d_in[18];
  const float* gam    = (const float*)d_in[19];
  const float* bet    = (const float*)d_in[20];

  char* ws = (char*)d_ws;
  int*      flag  = (int*)ws;                        // [0,4): mask-dtype flag
  int*      bars  = (int*)(ws + 256);                // per-dir step flags (2x8 ints)
  uint16_t* Xb    = (uint16_t*)(ws + 4096);          // 2 planes x 1280x320 bf16 (1,638,400 B)
  uint16_t* wihb  = (uint16_t*)(ws + 1642496);       // 4 planes x 1024x320 bf16 (2,621,440 B)
  float*    gbase = (float*)(ws + 4263936);          // 2x1280x1024 f32 (10,485,760 B)
  uint16_t* hbuf  = (uint16_t*)(ws + 14749696);      // 2dir x 2par x 2plane x 32x256 (131,072 B)

  hipMemsetAsync(d_ws, 0, 4096, stream);             // reset flag + step flags
  k_detect<<<1, 256, 0, stream>>>((const uint32_t*)xmask, flag);
  k_prep<<<1280, 256, 0, stream>>>(wih_f, wih_b, wihb);
  k_attn<<<NB * NS, 256, 0, stream>>>(x, xmask, xfeat, slen, emb, attn_w, Xb, flag);
  k_gbase<<<320, 512, 0, stream>>>(Xb, wihb, bih_f, bhh_f, bih_b, bhh_b, gbase);
  k_lstm<<<8, 512, 0, stream>>>(whh_f, whh_b, gbase, slen, hbuf, bars);
  k_final<<<1, 1024, 0, stream>>>(hbuf, fc_w, fc_b, gam, bet, (float*)d_out);
}

// Round 6
// 406.412 us; speedup vs baseline: 2.1946x; 2.1946x over previous
//
#include <hip/hip_runtime.h>
#include <stdint.h>

#define NB 32
#define NS 40
#define NT 60
#define NH 256
#define NF 64
#define NDIN 320
#define NG 1024
#define NSB 1280
#define NOUT 128

typedef __bf16 bf16x8 __attribute__((ext_vector_type(8)));
typedef float f32x4 __attribute__((ext_vector_type(4)));

union bfrag { bf16x8 v; uint16_t u[8]; uint4 q; uint64_t d[2]; };
union f4arr { float4 v; float a[4]; };
union f2arr { float2 v; float a[2]; };

__device__ __forceinline__ uint16_t f2bf(float f) {
  uint32_t u = __float_as_uint(f);
  u += 0x7fffu + ((u >> 16) & 1u);
  return (uint16_t)(u >> 16);
}
__device__ __forceinline__ float bf2f(uint16_t h) {
  return __uint_as_float(((uint32_t)h) << 16);
}
__device__ __forceinline__ float sigf(float x) { return 1.0f / (1.0f + expf(-x)); }

__device__ __forceinline__ uint64_t ld_agent_u64(const uint64_t* p) {
  return __hip_atomic_load(p, __ATOMIC_RELAXED, __HIP_MEMORY_SCOPE_AGENT);
}
__device__ __forceinline__ void st_agent_u64(uint64_t* p, uint64_t v) {
  __hip_atomic_store(p, v, __ATOMIC_RELAXED, __HIP_MEMORY_SCOPE_AGENT);
}
__device__ __forceinline__ uint32_t ld_agent_u32(const uint32_t* p) {
  return __hip_atomic_load(p, __ATOMIC_RELAXED, __HIP_MEMORY_SCOPE_AGENT);
}
__device__ __forceinline__ void st_agent_u32(uint32_t* p, uint32_t v) {
  __hip_atomic_store(p, v, __ATOMIC_RELAXED, __HIP_MEMORY_SCOPE_AGENT);
}

// ---------------- mask dtype detector: 0=int32, 1=bytes(bool), 2=float32 ----
__global__ void k_detect(const uint32_t* __restrict__ xm, int* __restrict__ flag) {
  __shared__ int s_notint, s_notflt;
  if (threadIdx.x == 0) { s_notint = 0; s_notflt = 0; }
  __syncthreads();
  int notint = 0, notflt = 0;
  for (int i = threadIdx.x; i < 19200; i += 256) {   // 76800 bytes: safe all dtypes
    uint32_t v = xm[i];
    if (v > 1u) notint = 1;
    if (v != 0u && v != 0x3f800000u) notflt = 1;
  }
  if (notint) atomicOr(&s_notint, 1);
  if (notflt) atomicOr(&s_notflt, 1);
  __syncthreads();
  if (threadIdx.x == 0) {
    int f;
    if (!s_notint) f = 0;
    else if (!s_notflt) f = 2;
    else f = 1;
    *flag = f;
  }
}

// -------- wih -> hi/lo bf16 planes: layout [hi: dir0,dir1][lo: dir0,dir1] ----
__global__ void k_prep(const float* __restrict__ wf, const float* __restrict__ wb,
                       uint16_t* __restrict__ outw) {
  const int n = NG * NDIN;
  for (int idx = blockIdx.x * 256 + threadIdx.x; idx < 2 * n; idx += gridDim.x * 256) {
    float v = (idx < n) ? wf[idx] : wb[idx - n];
    uint16_t hi = f2bf(v);
    outw[idx] = hi;
    outw[2 * n + idx] = f2bf(v - bf2f(hi));
  }
}

// ---------------- attention pooling: one block per (b,s) --------------------
__global__ __launch_bounds__(256) void k_attn(
    const int* __restrict__ x, const void* __restrict__ xmask,
    const float* __restrict__ xfeat, const int* __restrict__ slen,
    const float* __restrict__ emb, const float* __restrict__ attn_w,
    uint16_t* __restrict__ Xb, const int* __restrict__ flagp)
{
  int bs = blockIdx.x;
  int b = bs / NS, s = bs % NS;
  int tid = threadIdx.x;
  uint16_t* Xh = Xb + (size_t)(s * NB + b) * NDIN;
  uint16_t* Xl = Xh + (size_t)NSB * NDIN;
  int len = slen[b];
  if (s >= len) {
    for (int i = tid; i < NDIN; i += 256) { Xh[i] = 0; Xl[i] = 0; }
    return;
  }
  __shared__ __attribute__((aligned(16))) float sw[NH];
  __shared__ float salpha[NT];
  __shared__ int sidx[NT];
  __shared__ unsigned char svalid[NT];
  __shared__ __attribute__((aligned(16))) uint16_t es[NT][NH];
  sw[tid] = attn_w[tid];
  int flag = *flagp;
  if (tid < NT) {
    int mi = bs * NT + tid;
    sidx[tid] = x[mi];
    int mv;
    if (flag == 1)      mv = ((const unsigned char*)xmask)[mi];
    else if (flag == 2) mv = (((const float*)xmask)[mi] != 0.0f) ? 1 : 0;
    else                mv = ((const int*)xmask)[mi];
    svalid[tid] = (mv == 0) ? 1 : 0;
  }
  __syncthreads();
  int wave = tid >> 6, lane = tid & 63;
  for (int t = wave; t < NT; t += 4) {
    float d = 0.0f;
    if (svalid[t]) {
      const float* er = emb + (size_t)sidx[t] * NH;
      float4 e4 = ((const float4*)er)[lane];
      float4 w4 = ((const float4*)sw)[lane];
      uint16_t* ed = &es[t][lane * 4];
      ed[0] = f2bf(e4.x); ed[1] = f2bf(e4.y); ed[2] = f2bf(e4.z); ed[3] = f2bf(e4.w);
      d = e4.x * w4.x + e4.y * w4.y + e4.z * w4.z + e4.w * w4.w;
      #pragma unroll
      for (int o = 32; o > 0; o >>= 1) d += __shfl_down(d, o);
    }
    if (lane == 0) salpha[t] = d;
  }
  __syncthreads();
  if (tid < 64) {                       // wave-parallel softmax over <=60 tokens
    int valid = (tid < NT) && svalid[tid];
    float v = valid ? salpha[tid] : -1e30f;
    float m = v;
    #pragma unroll
    for (int o = 32; o > 0; o >>= 1) m = fmaxf(m, __shfl_xor(m, o));
    float e = valid ? expf(v - m) : 0.0f;
    float ssum = e;
    #pragma unroll
    for (int o = 32; o > 0; o >>= 1) ssum += __shfl_xor(ssum, o);
    if (tid < NT) salpha[tid] = e / ssum;
  }
  __syncthreads();
  float acc = 0.0f;                     // emb_part, tid == h-index
  for (int t = 0; t < NT; t++) {
    float a = salpha[t];
    if (a != 0.0f) acc += a * bf2f(es[t][tid]);
  }
  {
    uint16_t hi = f2bf(acc);
    Xh[tid] = hi; Xl[tid] = f2bf(acc - bf2f(hi));
  }
  if (tid < NF) {
    float fa = 0.0f;
    const float* fp = xfeat + (size_t)bs * NT * NF + tid;
    for (int t = 0; t < NT; t++) if (svalid[t]) fa += fp[t * NF];
    uint16_t hi = f2bf(fa);
    Xh[NH + tid] = hi; Xl[NH + tid] = f2bf(fa - bf2f(hi));
  }
}

// ------- gbase = X @ wih^T + bih + bhh, hi/lo split operands ----------------
__global__ __launch_bounds__(512) void k_gbase(
    const uint16_t* __restrict__ Xb, const uint16_t* __restrict__ wihb,
    const float* __restrict__ bih_f, const float* __restrict__ bhh_f,
    const float* __restrict__ bih_b, const float* __restrict__ bhh_b,
    float* __restrict__ gbase)
{
  const int n = NG * NDIN;
  int wave = threadIdx.x >> 6, lane = threadIdx.x & 63;
  int job = blockIdx.x * 8 + wave;
  int dir = job / 1280;
  int r = job % 1280;
  int nt = r % 64, ms = r / 64;
  int m0 = ms * 64;
  const uint16_t* Wh = wihb + (size_t)dir * n;
  const uint16_t* Wl = Wh + (size_t)2 * n;
  const uint16_t* Ah = Xb;
  const uint16_t* Al = Xb + (size_t)NSB * NDIN;
  int lrow = lane & 15, lk = (lane >> 4) * 8;
  f32x4 acc0 = {0,0,0,0}, acc1 = acc0, acc2 = acc0, acc3 = acc0;
  for (int kk = 0; kk < 10; kk++) {
    int k0 = kk * 32 + lk;
    bfrag bh, bl, ah0, ah1, ah2, ah3, al0, al1, al2, al3;
    bh.q = *(const uint4*)(Wh + (size_t)(nt * 16 + lrow) * NDIN + k0);
    bl.q = *(const uint4*)(Wl + (size_t)(nt * 16 + lrow) * NDIN + k0);
    ah0.q = *(const uint4*)(Ah + (size_t)(m0 +  0 + lrow) * NDIN + k0);
    ah1.q = *(const uint4*)(Ah + (size_t)(m0 + 16 + lrow) * NDIN + k0);
    ah2.q = *(const uint4*)(Ah + (size_t)(m0 + 32 + lrow) * NDIN + k0);
    ah3.q = *(const uint4*)(Ah + (size_t)(m0 + 48 + lrow) * NDIN + k0);
    al0.q = *(const uint4*)(Al + (size_t)(m0 +  0 + lrow) * NDIN + k0);
    al1.q = *(const uint4*)(Al + (size_t)(m0 + 16 + lrow) * NDIN + k0);
    al2.q = *(const uint4*)(Al + (size_t)(m0 + 32 + lrow) * NDIN + k0);
    al3.q = *(const uint4*)(Al + (size_t)(m0 + 48 + lrow) * NDIN + k0);
    acc0 = __builtin_amdgcn_mfma_f32_16x16x32_bf16(ah0.v, bh.v, acc0, 0, 0, 0);
    acc0 = __builtin_amdgcn_mfma_f32_16x16x32_bf16(ah0.v, bl.v, acc0, 0, 0, 0);
    acc0 = __builtin_amdgcn_mfma_f32_16x16x32_bf16(al0.v, bh.v, acc0, 0, 0, 0);
    acc1 = __builtin_amdgcn_mfma_f32_16x16x32_bf16(ah1.v, bh.v, acc1, 0, 0, 0);
    acc1 = __builtin_amdgcn_mfma_f32_16x16x32_bf16(ah1.v, bl.v, acc1, 0, 0, 0);
    acc1 = __builtin_amdgcn_mfma_f32_16x16x32_bf16(al1.v, bh.v, acc1, 0, 0, 0);
    acc2 = __builtin_amdgcn_mfma_f32_16x16x32_bf16(ah2.v, bh.v, acc2, 0, 0, 0);
    acc2 = __builtin_amdgcn_mfma_f32_16x16x32_bf16(ah2.v, bl.v, acc2, 0, 0, 0);
    acc2 = __builtin_amdgcn_mfma_f32_16x16x32_bf16(al2.v, bh.v, acc2, 0, 0, 0);
    acc3 = __builtin_amdgcn_mfma_f32_16x16x32_bf16(ah3.v, bh.v, acc3, 0, 0, 0);
    acc3 = __builtin_amdgcn_mfma_f32_16x16x32_bf16(ah3.v, bl.v, acc3, 0, 0, 0);
    acc3 = __builtin_amdgcn_mfma_f32_16x16x32_bf16(al3.v, bh.v, acc3, 0, 0, 0);
  }
  int col = nt * 16 + lrow;
  float bias = dir ? (bih_b[col] + bhh_b[col]) : (bih_f[col] + bhh_f[col]);
  float* gb = gbase + (size_t)dir * NSB * NG;
  int rb = (lane >> 4) * 4;
  #pragma unroll
  for (int rr = 0; rr < 4; rr++) {
    gb[(size_t)(m0 +  0 + rb + rr) * NG + col] = acc0[rr] + bias;
    gb[(size_t)(m0 + 16 + rb + rr) * NG + col] = acc1[rr] + bias;
    gb[(size_t)(m0 + 32 + rb + rr) * NG + col] = acc2[rr] + bias;
    gb[(size_t)(m0 + 48 + rb + rr) * NG + col] = acc3[rr] + bias;
  }
}

// ---------------- persistent bidirectional LSTM: 16 blocks ------------------
// 8 blocks per direction, each owns 32 hidden units (128 gate rows). Per-wave
// weight state = 16 frags = 64 VGPRs (register-resident). h exchange through
// L3 via agent-scope relaxed atomics; bulk-staged into LDS each step (R3
// pattern). Per-part step flags; poll skips own part.
__global__ __launch_bounds__(512, 2) void k_lstm(
    const float* __restrict__ whh_f_, const float* __restrict__ whh_b_,
    const float* __restrict__ gbase, const int* __restrict__ slen,
    uint16_t* __restrict__ hbuf, int* __restrict__ bars)
{
  int wg = blockIdx.x;
  int dir = wg >> 3, p = wg & 7;
  int u0 = p * 32;
  int tid = threadIdx.x, wave = tid >> 6, lane = tid & 63;
  const float* Wr = dir ? whh_b_ : whh_f_;
  const float* gb = gbase + (size_t)dir * NSB * NG;
  uint16_t* hb = hbuf + (size_t)dir * 4 * NB * NH;   // [parity][plane][NB][NH]
  int* sf = bars + dir * 16;

  __shared__ __attribute__((aligned(16))) uint16_t hs[2][NB][264];
  __shared__ float gbuf[NB][132];
  __shared__ float cbuf[NB][32];
  __shared__ int slen_s[NB];

  if (tid < NB) slen_s[tid] = slen[tid];
  for (int i2 = tid; i2 < NB * 32; i2 += 512) ((float*)cbuf)[i2 & (NB * 32 - 1)] = 0.0f;

  int lrow = lane & 15, lkb = (lane >> 4) * 8;
  // whh fragments, hi+lo: wave owns ONE n-tile (16 gate-rows of this part)
  bfrag wh[8], wl[8];
  {
    int nl = wave * 16 + lrow;                     // local n in [0,128)
    int grow_ = (nl >> 5) * 256 + u0 + (nl & 31);  // gate*256 + unit
    const float* wrow = Wr + (size_t)grow_ * NH;
    #pragma unroll
    for (int kk = 0; kk < 8; kk++) {
      int k0 = kk * 32 + lkb;
      bfrag th, tl;
      #pragma unroll
      for (int e = 0; e < 8; e++) {
        float v0 = wrow[k0 + e];
        uint16_t h0_ = f2bf(v0);
        th.u[e] = h0_; tl.u[e] = f2bf(v0 - bf2f(h0_));
      }
      wh[kk] = th; wl[kk] = tl;
    }
  }
  // zero h parity-0, both planes, this part's 32-unit slice: 512 u64
  {
    int pl = tid >> 8, r = tid & 255;
    int b2 = r >> 3, c3 = r & 7;                   // 8 u64 per 32-unit row
    st_agent_u64((uint64_t*)(hb + ((size_t)pl * NB + b2) * NH + u0) + c3, 0ull);
  }
  asm volatile("s_waitcnt vmcnt(0)" ::: "memory");
  __syncthreads();
  if (tid == 0) __hip_atomic_store(&sf[p], 1, __ATOMIC_RELAXED, __HIP_MEMORY_SCOPE_AGENT);

  int b_ = tid >> 4;
  int j0 = (tid & 15) * 2;                         // 2 units per thread

  for (int i = 0; i < NS; i++) {
    int t = dir ? (NS - 1 - i) : i;
    const uint16_t* hp = hb + (size_t)(i & 1) * 2 * NB * NH;
    // ---- prefetch this step's gbase values + own passthrough h bits ----
    const float* growp = gb + ((size_t)t * NB + b_) * NG;
    f2arr g0, g1, g2, g3;
    g0.v = *(const float2*)(growp + u0 + j0);
    g1.v = *(const float2*)(growp + 256 + u0 + j0);
    g2.v = *(const float2*)(growp + 512 + u0 + j0);
    g3.v = *(const float2*)(growp + 768 + u0 + j0);
    uint32_t ph  = ld_agent_u32((const uint32_t*)(hp + (size_t)b_ * NH + u0 + j0));
    uint32_t plo = ld_agent_u32((const uint32_t*)(hp + (size_t)(NB + b_) * NH + u0 + j0));
    // ---- poll: other 7 parts published h for this step (tid 0 only) ----
    if (tid == 0) {
      int need = i + 1;
      long spins = 0;
      for (;;) {
        int ok = 1;
        #pragma unroll
        for (int q = 0; q < 8; q++) {
          if (q == p) continue;
          int v = __hip_atomic_load(&sf[q], __ATOMIC_RELAXED, __HIP_MEMORY_SCOPE_AGENT);
          ok &= (v >= need);
        }
        if (ok) break;
        if (++spins > (1L << 22)) break;
        __builtin_amdgcn_s_sleep(1);
      }
    }
    __syncthreads();
    // ---- bulk-stage full h (both planes) into LDS: 8 u64 per thread ----
    {
      const uint64_t* hp64 = (const uint64_t*)hp;
      uint64_t tmp[8];
      #pragma unroll
      for (int q = 0; q < 8; q++)
        tmp[q] = ld_agent_u64(hp64 + tid + q * 512);
      #pragma unroll
      for (int q = 0; q < 8; q++) {
        int i3 = tid + q * 512;
        int pl = i3 >> 11, r = i3 & 2047;
        int bb = r >> 6, c8 = r & 63;
        *(uint64_t*)(&hs[pl][bb][c8 * 4]) = tmp[q];
      }
    }
    __syncthreads();
    // ---- recurrent GEMM: acc[m][n] = Ah*Wh + Ah*Wl + Al*Wh ----
    f32x4 acc0 = {0,0,0,0}, acc1 = acc0;
    #pragma unroll
    for (int kk = 0; kk < 8; kk++) {
      int k0 = kk * 32 + lkb;
      bfrag ah0, ah1, al0, al1;
      ah0.q = *(const uint4*)(&hs[0][lrow][k0]);
      ah1.q = *(const uint4*)(&hs[0][16 + lrow][k0]);
      al0.q = *(const uint4*)(&hs[1][lrow][k0]);
      al1.q = *(const uint4*)(&hs[1][16 + lrow][k0]);
      acc0 = __builtin_amdgcn_mfma_f32_16x16x32_bf16(ah0.v, wh[kk].v, acc0, 0, 0, 0);
      acc0 = __builtin_amdgcn_mfma_f32_16x16x32_bf16(ah0.v, wl[kk].v, acc0, 0, 0, 0);
      acc0 = __builtin_amdgcn_mfma_f32_16x16x32_bf16(al0.v, wh[kk].v, acc0, 0, 0, 0);
      acc1 = __builtin_amdgcn_mfma_f32_16x16x32_bf16(ah1.v, wh[kk].v, acc1, 0, 0, 0);
      acc1 = __builtin_amdgcn_mfma_f32_16x16x32_bf16(ah1.v, wl[kk].v, acc1, 0, 0, 0);
      acc1 = __builtin_amdgcn_mfma_f32_16x16x32_bf16(al1.v, wh[kk].v, acc1, 0, 0, 0);
    }
    {
      int nl = wave * 16 + lrow;
      int rb = (lane >> 4) * 4;
      #pragma unroll
      for (int rr = 0; rr < 4; rr++) {
        gbuf[rb + rr][nl]      = acc0[rr];
        gbuf[16 + rb + rr][nl] = acc1[rr];
      }
    }
    __syncthreads();
    // ---- pointwise: thread owns (b, 2 units); g + passthrough in registers --
    {
      int upd = (t < slen_s[b_]) ? 1 : 0;
      uint32_t hiw = 0, low = 0;
      #pragma unroll
      for (int e = 0; e < 2; e++) {
        int j = j0 + e;
        float gi = gbuf[b_][j]      + g0.a[e];
        float gf = gbuf[b_][32 + j] + g1.a[e];
        float gg = gbuf[b_][64 + j] + g2.a[e];
        float go = gbuf[b_][96 + j] + g3.a[e];
        float c_old = cbuf[b_][j];
        float c2v = sigf(gf) * c_old + sigf(gi) * tanhf(gg);
        float h2v = sigf(go) * tanhf(c2v);
        cbuf[b_][j] = upd ? c2v : c_old;
        uint16_t hb_, lb_;
        if (upd) { hb_ = f2bf(h2v); lb_ = f2bf(h2v - bf2f(hb_)); }
        else     { hb_ = (uint16_t)(ph >> (16 * e)); lb_ = (uint16_t)(plo >> (16 * e)); }
        hiw |= ((uint32_t)hb_) << (16 * e);
        low |= ((uint32_t)lb_) << (16 * e);
      }
      size_t pbase = (size_t)(((i + 1) & 1) * 2) * NB * NH;
      st_agent_u32((uint32_t*)(hb + pbase + (size_t)b_ * NH + u0 + j0), hiw);
      st_agent_u32((uint32_t*)(hb + pbase + (size_t)(NB + b_) * NH + u0 + j0), low);
    }
    asm volatile("s_waitcnt vmcnt(0)" ::: "memory");   // drain h stores (per wave)
    __syncthreads();                                    // all waves drained
    if (tid == 0)
      __hip_atomic_store(&sf[p], i + 2, __ATOMIC_RELAXED, __HIP_MEMORY_SCOPE_AGENT);
  }
}

// ---------------- FC + BatchNorm + ReLU + log_softmax(axis=0) ---------------
__global__ __launch_bounds__(1024) void k_final(
    const uint16_t* __restrict__ hbuf, const float* __restrict__ fc_w,
    const float* __restrict__ fc_b, const float* __restrict__ gamma_,
    const float* __restrict__ beta_, float* __restrict__ outp)
{
  __shared__ float hid[NB][512];
  __shared__ float ylds[NB][NOUT];
  int tid = threadIdx.x;
  const uint16_t* hf  = hbuf;                       // dir0 parity0 (hi +0, lo +NB*NH)
  const uint16_t* hbk = hbuf + (size_t)4 * NB * NH; // dir1 parity0
  for (int idx = tid; idx < NB * 512; idx += 1024) {
    int bb = idx >> 9, k = idx & 511;
    int bsrc = 2 * (bb & 15) + (k >> 8);
    int hcol = k & 255;
    const uint16_t* src = (bb < 16) ? hf : hbk;
    hid[bb][k] = bf2f(src[bsrc * NH + hcol]) + bf2f(src[NB * NH + bsrc * NH + hcol]);
  }
  __syncthreads();
  int o = tid & 127, b0 = tid >> 7;
  float a0 = 0, a1 = 0, a2 = 0, a3 = 0;
  const float4* wrow = (const float4*)(fc_w + (size_t)o * 512);
  for (int k4 = 0; k4 < 128; k4++) {
    float4 w = wrow[k4];
    float4 h0 = *(const float4*)(&hid[b0][k4 * 4]);
    float4 h1 = *(const float4*)(&hid[b0 + 8][k4 * 4]);
    float4 h2 = *(const float4*)(&hid[b0 + 16][k4 * 4]);
    float4 h3 = *(const float4*)(&hid[b0 + 24][k4 * 4]);
    a0 += w.x * h0.x + w.y * h0.y + w.z * h0.z + w.w * h0.w;
    a1 += w.x * h1.x + w.y * h1.y + w.z * h1.z + w.w * h1.w;
    a2 += w.x * h2.x + w.y * h2.y + w.z * h2.z + w.w * h2.w;
    a3 += w.x * h3.x + w.y * h3.y + w.z * h3.z + w.w * h3.w;
  }
  float bias = fc_b[o];
  ylds[b0][o]      = a0 + bias;
  ylds[b0 + 8][o]  = a1 + bias;
  ylds[b0 + 16][o] = a2 + bias;
  ylds[b0 + 24][o] = a3 + bias;
  __syncthreads();
  if (tid < NOUT) {
    float mu = 0;
    for (int bb = 0; bb < NB; bb++) mu += ylds[bb][tid];
    mu *= (1.0f / NB);
    float var = 0;
    for (int bb = 0; bb < NB; bb++) { float d = ylds[bb][tid] - mu; var += d * d; }
    var *= (1.0f / NB);
    float g = gamma_[tid], be = beta_[tid];
    float inv = 1.0f / sqrtf(var + 1e-5f);
    float ym = -1e30f;
    for (int bb = 0; bb < NB; bb++) {
      float y = g * (ylds[bb][tid] - mu) * inv + be;
      y = fmaxf(y, 0.0f);
      ylds[bb][tid] = y;
      if (y > ym) ym = y;
    }
    float se = 0;
    for (int bb = 0; bb < NB; bb++) se += expf(ylds[bb][tid] - ym);
    float lse = ym + logf(se);
    for (int bb = 0; bb < NB; bb++) outp[bb * NOUT + tid] = ylds[bb][tid] - lse;
  }
}

extern "C" void kernel_launch(void* const* d_in, const int* in_sizes, int n_in,
                              void* d_out, int out_size, void* d_ws, size_t ws_size,
                              hipStream_t stream) {
  (void)in_sizes; (void)n_in; (void)out_size; (void)ws_size;
  const int*   x      = (const int*)  d_in[0];
  const void*  xmask  =               d_in[1];
  const float* xfeat  = (const float*)d_in[2];
  const int*   slen   = (const int*)  d_in[3];
  const float* emb    = (const float*)d_in[6];
  const float* attn_w = (const float*)d_in[7];
  const float* wih_f  = (const float*)d_in[9];
  const float* whh_f  = (const float*)d_in[10];
  const float* bih_f  = (const float*)d_in[11];
  const float* bhh_f  = (const float*)d_in[12];
  const float* wih_b  = (const float*)d_in[13];
  const float* whh_b  = (const float*)d_in[14];
  const float* bih_b  = (const float*)d_in[15];
  const float* bhh_b  = (const float*)d_in[16];
  const float* fc_w   = (const float*)d_in[17];
  const float* fc_b   = (const float*)d_in[18];
  const float* gam    = (const float*)d_in[19];
  const float* bet    = (const float*)d_in[20];

  char* ws = (char*)d_ws;
  int*      flag  = (int*)ws;                        // [0,4): mask-dtype flag
  int*      bars  = (int*)(ws + 256);                // per-dir step flags (2x16 ints)
  uint16_t* Xb    = (uint16_t*)(ws + 4096);          // 2 planes x 1280x320 bf16 (1,638,400 B)
  uint16_t* wihb  = (uint16_t*)(ws + 1642496);       // 4 planes x 1024x320 bf16 (2,621,440 B)
  float*    gbase = (float*)(ws + 4263936);          // 2x1280x1024 f32 (10,485,760 B)
  uint16_t* hbuf  = (uint16_t*)(ws + 14749696);      // 2dir x 2par x 2plane x 32x256 (131,072 B)

  hipMemsetAsync(d_ws, 0, 4096, stream);             // reset flag + step flags
  k_detect<<<1, 256, 0, stream>>>((const uint32_t*)xmask, flag);
  k_prep<<<1280, 256, 0, stream>>>(wih_f, wih_b, wihb);
  k_attn<<<NB * NS, 256, 0, stream>>>(x, xmask, xfeat, slen, emb, attn_w, Xb, flag);
  k_gbase<<<320, 512, 0, stream>>>(Xb, wihb, bih_f, bhh_f, bih_b, bhh_b, gbase);
  k_lstm<<<16, 512, 0, stream>>>(whh_f, whh_b, gbase, slen, hbuf, bars);
  k_final<<<1, 1024, 0, stream>>>(hbuf, fc_w, fc_b, gam, bet, (float*)d_out);
}